// Round 12
// baseline (76.881 us; speedup 1.0000x reference)
//
#include <hip/hip_runtime.h>
#include <math.h>
#include <stdint.h>

// IntGELU — interval-hedged pipeline, v12: hot element math bit-identical to
// v11; structure reworked:
//  - ONE WAVE PER ROW (TPB=64): row reduce = 6 shfl_xor. No LDS, no
//    __syncthreads => no vmcnt-draining barrier; 12-deep load MLP per wave.
//  - emax chain cheapened with v6-proven EXACT substitutions: q via
//    t*rx0 estimate + exact-product fixup (not fp64 divide), 2^(23-q) via
//    bit-constructed double (not ldexp libcall). Bit-identical emax.
//  - rmax keeps the true fp64 divide (once per wave).

constexpr int H    = 3072;
constexpr int TPB  = 64;
constexpr int V4   = H / 4;       // 768 float4 per row
constexpr int LPW  = V4 / TPB;    // 12 float4 per lane

constexpr uint32_t MU32 = 2147483647u;
constexpr float    WT2  = 0.19365f * 0.5f;

// exact emax: bit-identical to floor-based fp64 ishift (v6-proven subs)
__device__ __forceinline__ uint32_t ishift_emax(double xi, double x0, double rx0d) {
    double t = (xi + floor(xi * 0.5)) - floor(xi * 0.0625);
    t = fmax(t, 23.0 * x0);
    double qe = t * rx0d;                      // >= 0 estimate of floor(t/x0)
    int qi = (int)qe; double qd = (double)qi;
    if (t > x0 * qd)               { qi -= 1; qd -= 1.0; }   // t/x0 < qi
    else if (t <= x0 * (qd + 1.0)) { qi += 1; qd += 1.0; }   // t/x0 >= qi+1
    double r  = t - x0 * qd;                   // exact product
    double e  = r * 0.5 - x0;
    double sc = __longlong_as_double((long long)(1046 - qi) << 52); // 2^(23-qi)
    double ei = floor(e * sc);                 // e*sc exact
    return (uint32_t)fmax(ei, 0.0);
}

// one +-1 remainder fixup: exact when |q0 - floor(M/s)| <= 1
__device__ __forceinline__ uint32_t fix1(uint32_t q, uint32_t su) {
    uint32_t p = q * su;                       // <= M+s < 2^32
    return (p > MU32) ? (q - 1u) : ((MU32 - p >= su) ? (q + 1u) : q);
}

// front chain + hedge corners; one rcp. (bit-identical to v11)
__device__ __forceinline__ void corners(float xv, float xmf, float rsff,
                                        float mx0f, float n23x0f, float rx0f,
                                        uint32_t emax_u,
                                        uint32_t& sigLo, uint32_t& sigHi,
                                        float& eiarg)
{
    float xi = (xv - xmf) * rsff;              // <= ~0
    float t  = (xi + floorf(xi * 0.5f)) - floorf(xi * 0.0625f);
    t = fmaxf(t, n23x0f);
    int   qi = (int)(t * rx0f);                // q in [0,23]
    float qd = (float)qi;
    float r  = fmaf(mx0f, qd, t);              // t - x0*q
    float e  = fmaf(r, 0.5f, mx0f);            // e in [15, 30]
    float scale = __int_as_float((150 - qi) << 23);   // 2^(23-q)
    eiarg = e * scale;

    float del = fmaf(6.0e-5f, scale, fmaf(1.6e-7f, eiarg, 3.0f));
    uint32_t uL = (uint32_t)(eiarg - del);     // eiarg-del >= 11.9 > 0
    uint32_t uH = (uint32_t)(eiarg + del);
    uint32_t sL = uL + emax_u;
    uint32_t sH = uH + emax_u;

    float sLf = (float)sL;
#if __has_builtin(__builtin_amdgcn_rcpf)
    float rfL = __builtin_amdgcn_rcpf(sLf);
#else
    float rfL = 1.0f / sLf;
#endif
    float dsf = (float)(sH - sL);
    float rfH = rfL * fmaf(-dsf, rfL, 1.0f);   // ~1/sH, rel err 2.2e-7
    uint32_t FH = fix1((uint32_t)(2147483648.0f * rfL), sL);  // floor(M/sL)
    uint32_t FL = fix1((uint32_t)(2147483648.0f * rfH), sH);  // floor(M/sH)

    sigLo = (uL * FL) >> 24;                   // products <= ~M, no wrap
    sigHi = (uH * FH) >> 24;
}

// rare path: exact v10/v11 semantics (midpoint if W<=thr else base)
__device__ __noinline__ float elem_full(float xv, float xmf, float rsff,
                                        float mx0f, float n23x0f, float rx0f,
                                        uint32_t emax_u)
{
    uint32_t sigLo, sigHi; float eiarg;
    corners(xv, xmf, rsff, mx0f, n23x0f, rx0f, emax_u, sigLo, sigHi, eiarg);
    float m05 = xv * 0.00390625f;
    float W = fabsf(m05) * (float)(sigHi - sigLo);
    if (W <= WT2) return m05 * (float)(sigLo + sigHi);
    uint32_t ei_u = (uint32_t)eiarg;
    uint32_t sb   = ei_u + emax_u;
    float sbf = (float)sb;
#if __has_builtin(__builtin_amdgcn_rcpf)
    float rfb = __builtin_amdgcn_rcpf(sbf);
#else
    float rfb = 1.0f / sbf;
#endif
    uint32_t fb   = fix1((uint32_t)(2147483648.0f * rfb), sb);
    uint32_t sigb = (ei_u * fb) >> 24;
    return (xv * 0.0078125f) * (float)sigb;
}

__global__ __launch_bounds__(TPB) void ig_ivhedge_v12(
    const float* __restrict__ xin, const float* __restrict__ sfin,
    float* __restrict__ yout, int nrow)
{
    const int row = blockIdx.x;
    const int l   = threadIdx.x;   // lane, 0..63

    const double sfd = (double)sfin[0];
    const double x0  = floor(-1.0 / (sfd * 1.702));  // -30 for sf=0.02
    const float rsff   = (float)(1.0 / sfd);
    const float mx0f   = (float)(-x0);               // 30, exact
    const float n23x0f = (float)(23.0 * x0);         // -690, exact
    const float rx0f   = (float)(1.0 / x0);
    const double rx0d  = (double)rx0f;               // estimator only (fixup exact)
    const double osf   = sfd * 0.0078125;

    const float4* xv4 = reinterpret_cast<const float4*>(xin) + (size_t)row * V4;
    float4*       yv4 = reinterpret_cast<float4*>(yout)      + (size_t)row * V4;

    // Load whole row into registers (12 float4/lane), lane-local max.
    float4 keep[LPW];
    float mx = -3.402823466e38f;
#pragma unroll
    for (int i = 0; i < LPW; ++i) {
        float4 w = xv4[l + i * TPB];
        keep[i] = w;
        mx = fmaxf(fmaxf(mx, fmaxf(w.x, w.y)), fmaxf(w.z, w.w));
    }
    // Wave-wide max: 6 shfl_xor, no LDS, no barrier.
#pragma unroll
    for (int d = 32; d >= 1; d >>= 1)
        mx = fmaxf(mx, __shfl_xor(mx, d, 64));

    const double rmax = (double)mx / sfd;            // true fp64 divide (ref-faithful)
    const uint32_t emax_u = ishift_emax(-rmax, x0, rx0d);

    uint32_t dmax = 0u;
#pragma unroll
    for (int i = 0; i < LPW; ++i) {
        float in4[4] = {keep[i].x, keep[i].y, keep[i].z, keep[i].w};
        float ou4[4];
#pragma unroll
        for (int j = 0; j < 4; ++j) {
            uint32_t sigLo, sigHi; float eiarg;
            corners(in4[j], mx, rsff, mx0f, n23x0f, rx0f, emax_u,
                    sigLo, sigHi, eiarg);
            dmax = max(dmax, sigHi - sigLo);
            ou4[j] = (in4[j] * 0.00390625f) * (float)(sigLo + sigHi);
        }
        float4 o; o.x = ou4[0]; o.y = ou4[1]; o.z = ou4[2]; o.w = ou4[3];
        yv4[l + i * TPB] = o;
    }

    // dsig <= 2 => W <= 2*|x|/256 < WT2 for |x| <= 12: no fallback possible.
    // dsig >= 3 is ~1e-6/elem — this block ~never executes.
    if (__any(dmax >= 3u)) {
#pragma unroll
        for (int i = 0; i < LPW; ++i) {
            float in4[4] = {keep[i].x, keep[i].y, keep[i].z, keep[i].w};
            float ou4[4];
#pragma unroll
            for (int j = 0; j < 4; ++j)
                ou4[j] = elem_full(in4[j], mx, rsff, mx0f, n23x0f, rx0f, emax_u);
            float4 o; o.x = ou4[0]; o.y = ou4[1]; o.z = ou4[2]; o.w = ou4[3];
            yv4[l + i * TPB] = o;
        }
    }

    if (row == 0 && l == 0) yout[(size_t)nrow * H] = (float)osf;
}

extern "C" void kernel_launch(void* const* d_in, const int* in_sizes, int n_in,
                              void* d_out, int out_size, void* d_ws, size_t ws_size,
                              hipStream_t stream) {
    const float* x  = (const float*)d_in[0];
    const float* sf = (const float*)d_in[1];
    float* out = (float*)d_out;
    const int total = in_sizes[0];       // 64*196*3072
    const int nrow  = total / H;         // 12544
    ig_ivhedge_v12<<<nrow, TPB, 0, stream>>>(x, sf, out, nrow);
}

// Round 13
// 64.262 us; speedup vs baseline: 1.1964x; 1.1964x over previous
//
#include <hip/hip_runtime.h>
#include <math.h>
#include <stdint.h>

// IntGELU — interval-hedged pipeline, v13: all-f32, slot-minimized.
//  - emax via the SAME f32 front chain at xv=0 (−x_int_max == (0−xm)/sf);
//    f32-emax deviates <= ~3 units vs fp64 — absorbed by slack 3 -> 8.
//  - del = 4.4e-6*eiarg + 8  (>= old 6e-5*scale + 1.6e-7*eiarg + 3, since
//    eiarg = e*scale with e in (15,30]); 'scale' then unused ->
//    eiarg = ldexpf(e, 23-q) = one v_ldexp_f32.
//  - exact floor((2^31-1)/s) with ONE-SIDED fixup: q0=(u32)(C*rcp(s)) with
//    C = 2^31-768 (bias −3.57e-7; total fp error <= 2.4e-7) => estimate
//    error strictly in (−1, 0] => q0 in {F−1, F}; single +1 fixup.
//  - hedge/midpoint/W-guard semantics unchanged from v10-v12.

constexpr int H   = 3072;
constexpr int TPB = 256;
constexpr int V4  = H / 4;     // 768 float4 per row
constexpr int PER = V4 / TPB;  // 3 float4 per thread

constexpr uint32_t MU32  = 2147483647u;
constexpr float    CBIAS = 2147482880.0f;   // 2^31 - 768, representable
constexpr float    WT2   = 0.19365f * 0.5f;

// q0 in {F-1, F} guaranteed -> one upward fixup gives exact floor(M/s)
__device__ __forceinline__ uint32_t fix_up(uint32_t q, uint32_t s) {
    uint32_t rem = MU32 - q * s;            // q*s <= M (q <= F) -> no wrap
    return q + ((rem >= s) ? 1u : 0u);
}

// f32 front chain: x -> eiarg (e * 2^(23-q)); replicates the ref's
// shift-exp range reduction (continuous across q boundaries)
__device__ __forceinline__ float eiarg_f(float xv, float xmf, float rsff,
                                         float mx0f, float n23x0f, float rx0f)
{
    float xi = (xv - xmf) * rsff;           // <= ~0
    float t  = (xi + floorf(xi * 0.5f)) - floorf(xi * 0.0625f);
    t = fmaxf(t, n23x0f);
    float tq = t * rx0f;                    // >= 0
    int   qi = (int)tq;                     // q in [0,23], trunc==floor
    float qd = (float)qi;
    float r  = fmaf(mx0f, qd, t);           // t - x0*q
    float e  = fmaf(r, 0.5f, mx0f);         // e in (15, 30]
    return ldexpf(e, 23 - qi);              // v_ldexp_f32
}

// hedge corners: 2 rcp + 2 one-sided-fixup exact divisions
__device__ __forceinline__ void corners2(float eiarg, uint32_t emax_u,
                                         uint32_t& sigLo, uint32_t& sigHi)
{
    float del = fmaf(4.4e-6f, eiarg, 8.0f);
    uint32_t uL = (uint32_t)(eiarg - del);  // eiarg-del >= 7 > 0
    uint32_t uH = (uint32_t)(eiarg + del);
    uint32_t sL = uL + emax_u;
    uint32_t sH = uH + emax_u;
#if __has_builtin(__builtin_amdgcn_rcpf)
    float rfL = __builtin_amdgcn_rcpf((float)sL);
    float rfH = __builtin_amdgcn_rcpf((float)sH);
#else
    float rfL = 1.0f / (float)sL;
    float rfH = 1.0f / (float)sH;
#endif
    uint32_t FH = fix_up((uint32_t)(CBIAS * rfL), sL);   // floor(M/sL)
    uint32_t FL = fix_up((uint32_t)(CBIAS * rfH), sH);   // floor(M/sH)
    sigLo = (uL * FL) >> 24;               // products <= ~1.1*M < 2^32
    sigHi = (uH * FH) >> 24;
}

// rare path (dsig >= 3 in wave): exact v10 semantics (midpoint or base)
__device__ __noinline__ float elem_full(float xv, float xmf, float rsff,
                                        float mx0f, float n23x0f, float rx0f,
                                        uint32_t emax_u)
{
    float eiarg = eiarg_f(xv, xmf, rsff, mx0f, n23x0f, rx0f);
    uint32_t sigLo, sigHi;
    corners2(eiarg, emax_u, sigLo, sigHi);
    float m05 = xv * 0.00390625f;
    float W = fabsf(m05) * (float)(sigHi - sigLo);
    if (W <= WT2) return m05 * (float)(sigLo + sigHi);
    uint32_t ei_u = (uint32_t)eiarg;
    uint32_t sb   = ei_u + emax_u;
#if __has_builtin(__builtin_amdgcn_rcpf)
    float rfb = __builtin_amdgcn_rcpf((float)sb);
#else
    float rfb = 1.0f / (float)sb;
#endif
    uint32_t fb   = fix_up((uint32_t)(CBIAS * rfb), sb);
    uint32_t sigb = (ei_u * fb) >> 24;
    return (xv * 0.0078125f) * (float)sigb;
}

__global__ __launch_bounds__(TPB) void ig_ivhedge_v13(
    const float* __restrict__ xin, const float* __restrict__ sfin,
    float* __restrict__ yout, int nrow)
{
    const int r0 = blockIdx.x;
    const int tx = threadIdx.x;

    const float sff    = sfin[0];
    const float rsff   = 1.0f / sff;                 // estimator-grade (hedged)
    const double x0d   = floor(-1.0 / ((double)sff * 1.702));
    const float mx0f   = (float)(-x0d);              // 30, exact
    const float n23x0f = (float)(23.0 * x0d);        // -690, exact
    const float rx0f   = (float)(1.0 / x0d);
    const float osf    = sff * 0.0078125f;

    const float4* xv4 = reinterpret_cast<const float4*>(xin) + (size_t)r0 * V4;
    float4*       yv4 = reinterpret_cast<float4*>(yout)      + (size_t)r0 * V4;

    // Pass 1: load row, per-thread max of raw x.
    float4 keep[PER];
    float mx = -3.402823466e38f;
#pragma unroll
    for (int i = 0; i < PER; ++i) {
        float4 w = xv4[tx + i * TPB];
        keep[i] = w;
        mx = fmaxf(fmaxf(mx, fmaxf(w.x, w.y)), fmaxf(w.z, w.w));
    }
#pragma unroll
    for (int d = 32; d >= 1; d >>= 1)
        mx = fmaxf(mx, __shfl_xor(mx, d, 64));
    __shared__ float smx[TPB / 64];
    if ((tx & 63) == 0) smx[tx >> 6] = mx;
    __syncthreads();
    float xm = smx[0];
#pragma unroll
    for (int wv = 1; wv < TPB / 64; ++wv) xm = fmaxf(xm, smx[wv]);

    // emax via the same f32 chain at xv = 0 (deviation absorbed by slack 8)
    const uint32_t emax_u =
        (uint32_t)eiarg_f(0.0f, xm, rsff, mx0f, n23x0f, rx0f);

    uint32_t dmax = 0u;
#pragma unroll
    for (int i = 0; i < PER; ++i) {
        float in4[4] = {keep[i].x, keep[i].y, keep[i].z, keep[i].w};
        float ou4[4];
#pragma unroll
        for (int j = 0; j < 4; ++j) {
            float eiarg = eiarg_f(in4[j], xm, rsff, mx0f, n23x0f, rx0f);
            uint32_t sigLo, sigHi;
            corners2(eiarg, emax_u, sigLo, sigHi);
            dmax = max(dmax, sigHi - sigLo);
            ou4[j] = (in4[j] * 0.00390625f) * (float)(sigLo + sigHi);
        }
        float4 o; o.x = ou4[0]; o.y = ou4[1]; o.z = ou4[2]; o.w = ou4[3];
        yv4[tx + i * TPB] = o;
    }

    // dsig <= 2 => W <= 2|x|/256 < WT2 for |x| <= 12: no fallback possible.
    if (__any(dmax >= 3u)) {
#pragma unroll
        for (int i = 0; i < PER; ++i) {
            float in4[4] = {keep[i].x, keep[i].y, keep[i].z, keep[i].w};
            float ou4[4];
#pragma unroll
            for (int j = 0; j < 4; ++j)
                ou4[j] = elem_full(in4[j], xm, rsff, mx0f, n23x0f, rx0f, emax_u);
            float4 o; o.x = ou4[0]; o.y = ou4[1]; o.z = ou4[2]; o.w = ou4[3];
            yv4[tx + i * TPB] = o;
        }
    }

    if (r0 == 0 && tx == 0) yout[(size_t)nrow * H] = osf;
}

extern "C" void kernel_launch(void* const* d_in, const int* in_sizes, int n_in,
                              void* d_out, int out_size, void* d_ws, size_t ws_size,
                              hipStream_t stream) {
    const float* x  = (const float*)d_in[0];
    const float* sf = (const float*)d_in[1];
    float* out = (float*)d_out;
    const int total = in_sizes[0];       // 64*196*3072
    const int nrow  = total / H;         // 12544
    ig_ivhedge_v13<<<nrow, TPB, 0, stream>>>(x, sf, out, nrow);
}